// Round 5
// baseline (1894.664 us; speedup 1.0000x reference)
//
#include <hip/hip_runtime.h>
#include <cstdint>

// ElmanRNN: B=64, T=1024, I=H=256, fp32.
//   layer: xp = X @ W_ih^T + b ; h_t = tanh(xp_t + h_{t-1} @ W_hh^T)
// Plan: GEMM0 (xp0 -> ws) ; scan0 (y0 -> d_out) ; GEMM1 (xp1 -> ws) ; scan1 (-> d_out)
// Requires ws_size >= 64 MB.
//
// R4 scan: R3 structure (16 waves, j=wave*16+(lane>>2), q=lane&3, intra-wave
// shfl reduce, padded double-buffered h, 1 barrier/step) PLUS:
//  - weights pinned in VGPRs via empty asm "+v" (defeats rematerialization;
//    R3's VGPR_Count=48 proved the compiler was re-loading W_hh every step)
//  - inner loop split in two halves by sched_barrier(0) to bound transient
//    LDS-temp pressure (keep peak regs < 128 cap at 4 waves/SIMD)

#define HDIM 256
#define TLEN 1024
#define BATCH 64
#define HQ 68   // padded LDS quarter stride (floats)

// ---------------------------------------------------------------------------
// Input-projection GEMM (unchanged from R1).
// ---------------------------------------------------------------------------
__global__ __launch_bounds__(256) void proj_gemm(
    const float* __restrict__ X,
    const float* __restrict__ W,
    const float* __restrict__ bias,
    float* __restrict__ C, int M)
{
    __shared__ __align__(16) float Ast[16][136];
    __shared__ __align__(16) float Bst[16][68];

    const int tid = threadIdx.x;
    const int tx  = tid & 15;
    const int ty  = tid >> 4;
    const int m0  = blockIdx.x * 128;
    const int n0  = blockIdx.y * 64;

    float acc[8][4];
#pragma unroll
    for (int i = 0; i < 8; ++i)
#pragma unroll
        for (int j = 0; j < 4; ++j) acc[i][j] = 0.f;

    const int ar = tid >> 1;
    const int ah = (tid & 1) * 8;
    const int bn = tid >> 2;
    const int bg = (tid & 3) * 4;

    for (int kc = 0; kc < 16; ++kc) {
        const int k0 = kc * 16;
        const float4 av0 = *reinterpret_cast<const float4*>(&X[(size_t)(m0 + ar) * HDIM + k0 + ah]);
        const float4 av1 = *reinterpret_cast<const float4*>(&X[(size_t)(m0 + ar) * HDIM + k0 + ah + 4]);
        const float4 bv  = *reinterpret_cast<const float4*>(&W[(size_t)(n0 + bn) * HDIM + k0 + bg]);
        __syncthreads();
        Ast[ah + 0][ar] = av0.x; Ast[ah + 1][ar] = av0.y;
        Ast[ah + 2][ar] = av0.z; Ast[ah + 3][ar] = av0.w;
        Ast[ah + 4][ar] = av1.x; Ast[ah + 5][ar] = av1.y;
        Ast[ah + 6][ar] = av1.z; Ast[ah + 7][ar] = av1.w;
        Bst[bg + 0][bn] = bv.x;  Bst[bg + 1][bn] = bv.y;
        Bst[bg + 2][bn] = bv.z;  Bst[bg + 3][bn] = bv.w;
        __syncthreads();
#pragma unroll
        for (int kk = 0; kk < 16; ++kk) {
            const float4 a0 = *reinterpret_cast<const float4*>(&Ast[kk][ty * 8]);
            const float4 a1 = *reinterpret_cast<const float4*>(&Ast[kk][ty * 8 + 4]);
            const float4 b4 = *reinterpret_cast<const float4*>(&Bst[kk][tx * 4]);
            const float av[8] = {a0.x, a0.y, a0.z, a0.w, a1.x, a1.y, a1.z, a1.w};
            const float bb[4] = {b4.x, b4.y, b4.z, b4.w};
#pragma unroll
            for (int i = 0; i < 8; ++i)
#pragma unroll
                for (int j = 0; j < 4; ++j)
                    acc[i][j] = fmaf(av[i], bb[j], acc[i][j]);
        }
    }

    const float4 bias4 = *reinterpret_cast<const float4*>(&bias[n0 + tx * 4]);
    const float bb[4] = {bias4.x, bias4.y, bias4.z, bias4.w};
#pragma unroll
    for (int i = 0; i < 8; ++i) {
        float4 o;
        o.x = acc[i][0] + bb[0];
        o.y = acc[i][1] + bb[1];
        o.z = acc[i][2] + bb[2];
        o.w = acc[i][3] + bb[3];
        *reinterpret_cast<float4*>(&C[(size_t)(m0 + ty * 8 + i) * HDIM + n0 + tx * 4]) = o;
    }
}

// ---------------------------------------------------------------------------
// R4 recurrent scan.
// ---------------------------------------------------------------------------
__device__ __forceinline__ float fast_tanh(float x)
{
    const float xc = fminf(fmaxf(x, -15.f), 15.f);
    const float e  = __expf(2.f * xc);
    return (e - 1.f) / (e + 1.f);
}

// Pin a float4's components into VGPRs; post-asm values are opaque to the
// compiler, so it cannot rematerialize them from memory inside the loop.
#define PIN4(V) asm volatile("" : "+v"((V).x), "+v"((V).y), "+v"((V).z), "+v"((V).w))

// One float4 of h against one float4 of weights.
#define STEP4(WC, IDX, SACC)                                                  \
    {                                                                         \
        const float4 hh = *reinterpret_cast<const float4*>(hb + (IDX) * 4);   \
        SACC = fmaf((WC).x, hh.x, SACC); SACC = fmaf((WC).y, hh.y, SACC);     \
        SACC = fmaf((WC).z, hh.z, SACC); SACC = fmaf((WC).w, hh.w, SACC);     \
    }

__global__ __launch_bounds__(1024, 4) void elman_scan(
    const float* __restrict__ xp,   // [B, T, H]
    const float* __restrict__ Whh,  // [H, H]
    float* __restrict__ y,          // [B, T, H]
    int T)
{
    const int b    = blockIdx.x;
    const int tid  = threadIdx.x;
    const int lane = tid & 63;
    const int wave = tid >> 6;
    const int j    = wave * 16 + (lane >> 2);   // output index 0..255
    const int q    = lane & 3;                  // K-quarter

    // W_hh[j][q*64 .. q*64+63] in 16 pinned float4 registers.
    const float4* wp = reinterpret_cast<const float4*>(Whh + (size_t)j * HDIM + q * 64);
    float4 w0 = wp[0],  w1 = wp[1],  w2 = wp[2],  w3 = wp[3];
    float4 w4 = wp[4],  w5 = wp[5],  w6 = wp[6],  w7 = wp[7];
    float4 w8 = wp[8],  w9 = wp[9],  w10 = wp[10], w11 = wp[11];
    float4 w12 = wp[12], w13 = wp[13], w14 = wp[14], w15 = wp[15];
    PIN4(w0);  PIN4(w1);  PIN4(w2);  PIN4(w3);
    PIN4(w4);  PIN4(w5);  PIN4(w6);  PIN4(w7);
    PIN4(w8);  PIN4(w9);  PIN4(w10); PIN4(w11);
    PIN4(w12); PIN4(w13); PIN4(w14); PIN4(w15);

    __shared__ __align__(16) float hbuf[2][4 * HQ];

    const float* xrow = xp + (size_t)b * T * HDIM;
    float*       yrow = y  + (size_t)b * T * HDIM;

    const int hpos = (j >> 6) * HQ + (j & 63);
    if (q == 0) hbuf[0][hpos] = 0.f;

    float xv[4];
#pragma unroll
    for (int p = 0; p < 4; ++p) xv[p] = xrow[(size_t)p * HDIM + j];

    __syncthreads();

    int cur = 0;
    for (int t = 0; t < T; t += 4) {
#pragma unroll
        for (int p = 0; p < 4; ++p) {
            int tf = t + p + 4; tf = (tf < T) ? tf : (T - 1);
            const float xnew = xrow[(size_t)tf * HDIM + j];

            const float* hb = &hbuf[cur][q * HQ];
            float s0 = 0.f, s1 = 0.f, s2 = 0.f, s3 = 0.f;

            // first half: 8 float4 of h (<=32 temp VGPRs live)
            STEP4(w0, 0, s0);  STEP4(w1, 1, s1);
            STEP4(w2, 2, s2);  STEP4(w3, 3, s3);
            STEP4(w4, 4, s0);  STEP4(w5, 5, s1);
            STEP4(w6, 6, s2);  STEP4(w7, 7, s3);
            __builtin_amdgcn_sched_barrier(0);
            // second half
            STEP4(w8, 8, s0);   STEP4(w9, 9, s1);
            STEP4(w10, 10, s2); STEP4(w11, 11, s3);
            STEP4(w12, 12, s0); STEP4(w13, 13, s1);
            STEP4(w14, 14, s2); STEP4(w15, 15, s3);

            float s = (s0 + s1) + (s2 + s3);

            // intra-wave 4-lane reduction (no barrier)
            s += __shfl_xor(s, 1);
            s += __shfl_xor(s, 2);

            const float hn = fast_tanh(s + xv[p]);

            if (q == 0)      hbuf[cur ^ 1][hpos] = hn;
            else if (q == 1) yrow[(size_t)(t + p) * HDIM + j] = hn;

            xv[p] = xnew;
            cur ^= 1;
            __syncthreads();
        }
    }
}

// ---------------------------------------------------------------------------
extern "C" void kernel_launch(void* const* d_in, const int* in_sizes, int n_in,
                              void* d_out, int out_size, void* d_ws, size_t ws_size,
                              hipStream_t stream)
{
    const float* x     = (const float*)d_in[0];
    const float* W_ih0 = (const float*)d_in[1];
    const float* b_ih0 = (const float*)d_in[2];
    const float* W_hh0 = (const float*)d_in[3];
    const float* W_ih1 = (const float*)d_in[4];
    const float* b_ih1 = (const float*)d_in[5];
    const float* W_hh1 = (const float*)d_in[6];

    float* out = (float*)d_out;
    float* xp  = (float*)d_ws;          // needs 64 MB

    const int M = BATCH * TLEN;
    dim3 ggrid(M / 128, HDIM / 64);

    proj_gemm<<<ggrid, 256, 0, stream>>>(x,   W_ih0, b_ih0, xp, M);
    elman_scan<<<BATCH, 1024, 0, stream>>>(xp, W_hh0, out, TLEN);
    proj_gemm<<<ggrid, 256, 0, stream>>>(out, W_ih1, b_ih1, xp, M);
    elman_scan<<<BATCH, 1024, 0, stream>>>(xp, W_hh1, out, TLEN);
}